// Round 2
// baseline (336.466 us; speedup 1.0000x reference)
//
#include <hip/hip_runtime.h>

typedef __bf16 bf16x8 __attribute__((ext_vector_type(8)));
typedef float  f32x4  __attribute__((ext_vector_type(4)));

#define AS1 __attribute__((address_space(1)))
#define AS3 __attribute__((address_space(3)))

__device__ __forceinline__ float bf2f(ushort u) {
    union { unsigned int i; float f; } v; v.i = ((unsigned int)u) << 16; return v.f;
}
__device__ __forceinline__ ushort f2bf(float f) {
    union { float f; unsigned int i; } v; v.f = f;
    unsigned int i = v.i;
    unsigned int r = i + 0x7FFFu + ((i >> 16) & 1u);   // RNE
    return (ushort)(r >> 16);
}
__device__ __forceinline__ float bflo(unsigned int u) { return bf2f((ushort)(u & 0xFFFFu)); }
__device__ __forceinline__ float bfhi(unsigned int u) { return bf2f((ushort)(u >> 16)); }

// ---------------------------------------------------------------------------
// dtype sniff: bf16 N(0,1) data -> ~256/256 sane u16s; f32 data -> ~140/256
// ---------------------------------------------------------------------------
__global__ void sniff_k(const ushort* __restrict__ x, int* __restrict__ flag)
{
    const int lane = threadIdx.x;   // 64 threads
    int cnt = 0;
    #pragma unroll
    for (int r = 0; r < 4; r++) {
        const ushort u = x[lane + r * 64];
        const int e = (u >> 7) & 0xFF;
        if ((u & 0x7FFF) == 0 || (e >= 112 && e <= 141)) cnt++;
    }
    #pragma unroll
    for (int o = 32; o > 0; o >>= 1) cnt += __shfl_down(cnt, o);
    if (lane == 0) flag[0] = (cnt >= 224) ? 1 : 0;   // 1 = bf16 inputs, 0 = f32
}

// ---------------------------------------------------------------------------
// canonicalize all inputs into packed bf16 region (copy or f32->bf16 by flag)
// ---------------------------------------------------------------------------
struct CanonArgs {
    const void* src[20];
    int off[20];     // cumulative start offsets (elements), ascending
    int total;
};

__launch_bounds__(256)
__global__ void canon_k(CanonArgs a, ushort* __restrict__ dst, const int* __restrict__ flag)
{
    const int i = blockIdx.x * 256 + threadIdx.x;
    if (i >= a.total) return;
    const int fl = flag[0];
    int s = 0;
    #pragma unroll
    for (int t = 1; t < 20; t++) if (i >= a.off[t]) s = t;
    const int li = i - a.off[s];
    ushort v;
    if (fl) v = ((const ushort*)a.src[s])[li];
    else    v = f2bf(((const float*)a.src[s])[li]);
    dst[i] = v;
}

// ---------------------------------------------------------------------------
// GEMM: C[M,N] = act(A[M,K](bf16) @ W[N,K]^T(bf16) + bias[N])  (B^T layout)
// 256 threads = 4 waves, wave grid 2x2, MFMA 16x16x32 bf16, BK=32,
// global_load_lds width-16 staging (wave-uniform base + lane*16B rule).
// ---------------------------------------------------------------------------
template<int BM, int BN, int ACT, bool WF32, bool WBF16>
__launch_bounds__(256, 2)
__global__ void gemm_bt(const ushort* __restrict__ A, const ushort* __restrict__ W,
                        const ushort* __restrict__ bias,
                        float* __restrict__ Cf, ushort* __restrict__ Cb,
                        int M, int N, int K)
{
    constexpr int WMT = BM / 32;
    constexpr int WNT = BN / 32;
    __shared__ __align__(16) ushort As[BM * 32];
    __shared__ __align__(16) ushort Bs[BN * 32];
    const int tid  = threadIdx.x;
    const int wave = tid >> 6;
    const int lane = tid & 63;
    const int m0 = blockIdx.x * BM;
    const int n0 = blockIdx.y * BN;
    const int wm = (wave >> 1) * (BM / 2);
    const int wn = (wave & 1) * (BN / 2);
    const int lrow = lane & 15;
    const int quad = lane >> 4;

    f32x4 acc[WMT][WNT];
    #pragma unroll
    for (int i = 0; i < WMT; i++)
        #pragma unroll
        for (int j = 0; j < WNT; j++)
            #pragma unroll
            for (int r = 0; r < 4; r++) acc[i][j][r] = 0.f;

    for (int k0 = 0; k0 < K; k0 += 32) {
        #pragma unroll
        for (int t = 0; t < BM / 64; t++) {
            const int inst = t * 4 + wave;
            const int row  = inst * 16 + (lane >> 2);
            const int sub  = lane & 3;
            const ushort* gp = A + (size_t)(m0 + row) * K + (k0 + sub * 8);
            __builtin_amdgcn_global_load_lds((AS1 void*)(void*)gp,
                                             (AS3 void*)(As + inst * 512), 16, 0, 0);
        }
        #pragma unroll
        for (int t = 0; t < BN / 64; t++) {
            const int inst = t * 4 + wave;
            const int row  = inst * 16 + (lane >> 2);
            const int sub  = lane & 3;
            const ushort* gp = W + (size_t)(n0 + row) * K + (k0 + sub * 8);
            __builtin_amdgcn_global_load_lds((AS1 void*)(void*)gp,
                                             (AS3 void*)(Bs + inst * 512), 16, 0, 0);
        }
        __syncthreads();

        bf16x8 afr[WMT], bfr[WNT];
        #pragma unroll
        for (int i = 0; i < WMT; i++)
            afr[i] = *(const bf16x8*)&As[(wm + i * 16 + lrow) * 32 + quad * 8];
        #pragma unroll
        for (int j = 0; j < WNT; j++)
            bfr[j] = *(const bf16x8*)&Bs[(wn + j * 16 + lrow) * 32 + quad * 8];
        #pragma unroll
        for (int i = 0; i < WMT; i++)
            #pragma unroll
            for (int j = 0; j < WNT; j++)
                acc[i][j] = __builtin_amdgcn_mfma_f32_16x16x32_bf16(afr[i], bfr[j], acc[i][j], 0, 0, 0);
        __syncthreads();
    }

    // epilogue: C/D layout col(n)=lane&15, row(m)=quad*4+reg  [m89/m91]
    #pragma unroll
    for (int i = 0; i < WMT; i++) {
        const int gm = m0 + wm + i * 16 + quad * 4;
        #pragma unroll
        for (int j = 0; j < WNT; j++) {
            const int gn = n0 + wn + j * 16 + lrow;
            const float bv = bf2f(bias[gn]);
            #pragma unroll
            for (int r = 0; r < 4; r++) {
                float v = acc[i][j][r] + bv;
                if (ACT == 1) v = 0.5f * v * (1.f + erff(v * 0.70710678118654752f));
                const size_t off = (size_t)(gm + r) * N + gn;
                if (WF32)  Cf[off] = v;
                if (WBF16) Cb[off] = f2bf(v);
            }
        }
    }
}

// ---------------------------------------------------------------------------
// depthwise causal conv (DC=4) + SiLU.  xz:[8192,1024] (xi = cols 0..511)
// ---------------------------------------------------------------------------
__launch_bounds__(256)
__global__ void conv_silu_k(const ushort* __restrict__ xz, const ushort* __restrict__ cw,
                            const ushort* __restrict__ cb, ushort* __restrict__ xc)
{
    const int idx = blockIdx.x * 256 + threadIdx.x;
    const int d = idx & 511;
    const int t = idx >> 9;
    const int l = t & 2047;
    float s = bf2f(cb[d]);
    #pragma unroll
    for (int k = 0; k < 4; k++) {
        const int ls = l - 3 + k;
        if (ls >= 0)
            s += bf2f(xz[(size_t)(t - 3 + k) * 1024 + d]) * bf2f(cw[d * 4 + k]);
    }
    s = s / (1.f + __expf(-s));
    xc[idx] = f2bf(s);
}

// ---------------------------------------------------------------------------
// per-token: x_dbl[48] = xc_row @ x_proj_w^T ; dt = softplus(x_dbl[:16]@dtw^T + dtb)
// ---------------------------------------------------------------------------
__launch_bounds__(256)
__global__ void xproj_dt_k(const ushort* __restrict__ xc, const ushort* __restrict__ xpw,
                           const ushort* __restrict__ dtw, const ushort* __restrict__ dtb,
                           float* __restrict__ dt, float* __restrict__ Bso, float* __restrict__ Cso)
{
    __shared__ float xrow[512];
    __shared__ float xdbl[48];
    __shared__ float part[192];
    const int t   = blockIdx.x;
    const int tid = threadIdx.x;
    xrow[tid]       = bf2f(xc[(size_t)t * 512 + tid]);
    xrow[tid + 256] = bf2f(xc[(size_t)t * 512 + 256 + tid]);
    __syncthreads();
    if (tid < 192) {
        const int o  = tid >> 2;
        const int p  = tid & 3;
        const int k0 = p * 128;
        float s = 0.f;
        #pragma unroll 4
        for (int kk = 0; kk < 16; kk++) {
            const uint4 w = *(const uint4*)&xpw[o * 512 + k0 + kk * 8];
            const float* xr = &xrow[k0 + kk * 8];
            s += xr[0] * bflo(w.x) + xr[1] * bfhi(w.x)
               + xr[2] * bflo(w.y) + xr[3] * bfhi(w.y)
               + xr[4] * bflo(w.z) + xr[5] * bfhi(w.z)
               + xr[6] * bflo(w.w) + xr[7] * bfhi(w.w);
        }
        part[tid] = s;
    }
    __syncthreads();
    if (tid < 48) {
        const float v = part[tid * 4] + part[tid * 4 + 1] + part[tid * 4 + 2] + part[tid * 4 + 3];
        xdbl[tid] = v;
        if (tid >= 16 && tid < 32) Bso[(size_t)t * 16 + (tid - 16)] = v;
        if (tid >= 32)             Cso[(size_t)t * 16 + (tid - 32)] = v;
    }
    __syncthreads();
    for (int dd = tid; dd < 512; dd += 256) {
        const uint4 wa = *(const uint4*)&dtw[dd * 16];
        const uint4 wb = *(const uint4*)&dtw[dd * 16 + 8];
        float s = bf2f(dtb[dd]);
        s += xdbl[0]  * bflo(wa.x) + xdbl[1]  * bfhi(wa.x)
           + xdbl[2]  * bflo(wa.y) + xdbl[3]  * bfhi(wa.y)
           + xdbl[4]  * bflo(wa.z) + xdbl[5]  * bfhi(wa.z)
           + xdbl[6]  * bflo(wa.w) + xdbl[7]  * bfhi(wa.w)
           + xdbl[8]  * bflo(wb.x) + xdbl[9]  * bfhi(wb.x)
           + xdbl[10] * bflo(wb.y) + xdbl[11] * bfhi(wb.y)
           + xdbl[12] * bflo(wb.z) + xdbl[13] * bfhi(wb.z)
           + xdbl[14] * bflo(wb.w) + xdbl[15] * bfhi(wb.w);
        dt[(size_t)t * 512 + dd] = (s > 15.f) ? s : __logf(1.f + __expf(s));
    }
}

// ---------------------------------------------------------------------------
// chunked scan, 32 chunks x 64 steps.  grid (2 dblk, 32 chunk, 4 b), 256 thr
// ---------------------------------------------------------------------------
__launch_bounds__(256)
__global__ void scan1_k(const float* __restrict__ dt, const ushort* __restrict__ xc,
                        const float* __restrict__ Bsi, const ushort* __restrict__ Alog,
                        float* __restrict__ summ)
{
    __shared__ float Bsh[64 * 16];
    const int tid = threadIdx.x;
    const int c = blockIdx.y, b = blockIdx.z;
    const int t0 = b * 2048 + c * 64;
    for (int e = tid; e < 1024; e += 256) Bsh[e] = Bsi[(size_t)t0 * 16 + e];
    __syncthreads();
    const int d = blockIdx.x * 256 + tid;
    float A[16], h[16], p[16];
    #pragma unroll
    for (int n = 0; n < 16; n++) {
        A[n] = -__expf(bf2f(Alog[d * 16 + n]));
        h[n] = 0.f; p[n] = 1.f;
    }
    for (int i = 0; i < 64; i++) {
        const int t = t0 + i;
        const float dtv = dt[(size_t)t * 512 + d];
        const float xiv = bf2f(xc[(size_t)t * 512 + d]);
        const float dx = dtv * xiv;
        const float* Br = &Bsh[i * 16];
        #pragma unroll
        for (int n = 0; n < 16; n++) {
            const float da = __expf(dtv * A[n]);
            p[n] *= da;
            h[n] = da * h[n] + dx * Br[n];
        }
    }
    const size_t base = ((size_t)(b * 32 + c) * 32) * 512 + d;
    #pragma unroll
    for (int n = 0; n < 16; n++) summ[base + (size_t)n * 512] = p[n];
    #pragma unroll
    for (int n = 0; n < 16; n++) summ[base + (size_t)(16 + n) * 512] = h[n];
}

__launch_bounds__(512)
__global__ void combine_k(const float* __restrict__ summ, float* __restrict__ hin)
{
    const int b = blockIdx.x >> 4, n = blockIdx.x & 15;
    const int d = threadIdx.x;
    float h = 0.f;
    for (int c = 0; c < 32; c++) {
        hin[((size_t)((b * 32 + c) * 16 + n)) * 512 + d] = h;
        const size_t sb = ((size_t)((b * 32 + c) * 32 + n)) * 512 + d;
        h = summ[sb] * h + summ[sb + 8192];
    }
}

__launch_bounds__(256)
__global__ void scan2_k(const float* __restrict__ dt, const ushort* __restrict__ xc,
                        const float* __restrict__ Bsi, const float* __restrict__ Csi,
                        const ushort* __restrict__ Alog, const float* __restrict__ hin,
                        const ushort* __restrict__ xz, const ushort* __restrict__ Dssm,
                        ushort* __restrict__ y)
{
    __shared__ float Bsh[64 * 16];
    __shared__ float Csh[64 * 16];
    const int tid = threadIdx.x;
    const int c = blockIdx.y, b = blockIdx.z;
    const int t0 = b * 2048 + c * 64;
    for (int e = tid; e < 1024; e += 256) {
        Bsh[e] = Bsi[(size_t)t0 * 16 + e];
        Csh[e] = Csi[(size_t)t0 * 16 + e];
    }
    __syncthreads();
    const int d = blockIdx.x * 256 + tid;
    float A[16], h[16];
    #pragma unroll
    for (int n = 0; n < 16; n++) A[n] = -__expf(bf2f(Alog[d * 16 + n]));
    #pragma unroll
    for (int n = 0; n < 16; n++)
        h[n] = hin[((size_t)((b * 32 + c) * 16 + n)) * 512 + d];
    const float Dv = bf2f(Dssm[d]);
    for (int i = 0; i < 64; i++) {
        const int t = t0 + i;
        const float dtv = dt[(size_t)t * 512 + d];
        const float xiv = bf2f(xc[(size_t)t * 512 + d]);
        const float dx = dtv * xiv;
        const float* Br = &Bsh[i * 16];
        const float* Cr = &Csh[i * 16];
        float yv = 0.f;
        #pragma unroll
        for (int n = 0; n < 16; n++) {
            const float da = __expf(dtv * A[n]);
            h[n] = da * h[n] + dx * Br[n];
            yv += h[n] * Cr[n];
        }
        yv += xiv * Dv;
        const float zv = bf2f(xz[(size_t)t * 1024 + 512 + d]);
        yv *= zv / (1.f + __expf(-zv));
        y[(size_t)t * 512 + d] = f2bf(yv);
    }
}

// ---------------------------------------------------------------------------
// LayerNorms (D=256, one token per block).  ln1 reads x per flag dtype;
// ln2 writes d_out per flag dtype.
// ---------------------------------------------------------------------------
__launch_bounds__(256)
__global__ void ln1_k(const void* __restrict__ xin, const float* __restrict__ sout,
                      const ushort* __restrict__ g, const ushort* __restrict__ bb,
                      float* __restrict__ y1f, ushort* __restrict__ y1b,
                      const int* __restrict__ flag)
{
    __shared__ float red[8];
    const int t = blockIdx.x, i = threadIdx.x;
    const size_t off = (size_t)t * 256 + i;
    const int fl = flag[0];
    const float xv = fl ? bf2f(((const ushort*)xin)[off]) : ((const float*)xin)[off];
    const float v = xv + sout[off];
    float s = v;
    #pragma unroll
    for (int o = 32; o > 0; o >>= 1) s += __shfl_down(s, o);
    if ((i & 63) == 0) red[i >> 6] = s;
    __syncthreads();
    const float mean = (red[0] + red[1] + red[2] + red[3]) * (1.f / 256.f);
    const float dv = v - mean;
    float q = dv * dv;
    #pragma unroll
    for (int o = 32; o > 0; o >>= 1) q += __shfl_down(q, o);
    if ((i & 63) == 0) red[4 + (i >> 6)] = q;
    __syncthreads();
    const float var = (red[4] + red[5] + red[6] + red[7]) * (1.f / 256.f);
    const float out = dv * rsqrtf(var + 1e-5f) * bf2f(g[i]) + bf2f(bb[i]);
    y1f[off] = out;
    y1b[off] = f2bf(out);
}

__launch_bounds__(256)
__global__ void ln2_k(const float* __restrict__ y1f, const float* __restrict__ ffn,
                      const ushort* __restrict__ g, const ushort* __restrict__ bb,
                      void* __restrict__ out, const int* __restrict__ flag)
{
    __shared__ float red[8];
    const int t = blockIdx.x, i = threadIdx.x;
    const size_t off = (size_t)t * 256 + i;
    const int fl = flag[0];
    const float v = y1f[off] + ffn[off];
    float s = v;
    #pragma unroll
    for (int o = 32; o > 0; o >>= 1) s += __shfl_down(s, o);
    if ((i & 63) == 0) red[i >> 6] = s;
    __syncthreads();
    const float mean = (red[0] + red[1] + red[2] + red[3]) * (1.f / 256.f);
    const float dv = v - mean;
    float q = dv * dv;
    #pragma unroll
    for (int o = 32; o > 0; o >>= 1) q += __shfl_down(q, o);
    if ((i & 63) == 0) red[4 + (i >> 6)] = q;
    __syncthreads();
    const float var = (red[4] + red[5] + red[6] + red[7]) * (1.f / 256.f);
    const float o2 = dv * rsqrtf(var + 1e-5f) * bf2f(g[i]) + bf2f(bb[i]);
    if (fl) ((ushort*)out)[off] = f2bf(o2);
    else    ((float*)out)[off]  = o2;
}

// ---------------------------------------------------------------------------
extern "C" void kernel_launch(void* const* d_in, const int* in_sizes, int n_in,
                              void* d_out, int out_size, void* d_ws, size_t ws_size,
                              hipStream_t stream)
{
    char* ws = (char*)d_ws;
    int*    flag  = (int*)(ws + 0);
    ushort* canon = (ushort*)(ws + 256);

    // canonical region offsets (elements), packed
    static const int coff[20] = {
        0,        2097152,  2359296,  2360320,  2362368,
        2362880,  2387456,  2395648,  2396160,  2404352,
        2404864,  2535936,  2536192,  2536448,  2536704,
        2798848,  2799872,  3062016,  3062272,  3062528 };
    static const int ctot = 3062784;

    CanonArgs ca;
    for (int i = 0; i < 20; i++) { ca.src[i] = d_in[i]; ca.off[i] = coff[i]; }
    ca.total = ctot;

    const ushort* cx   = canon + coff[0];
    const ushort* cipw = canon + coff[1];
    const ushort* cipb = canon + coff[2];
    const ushort* ccw  = canon + coff[3];
    const ushort* ccb  = canon + coff[4];
    const ushort* cxpw = canon + coff[5];
    const ushort* cdtw = canon + coff[6];
    const ushort* cdtb = canon + coff[7];
    const ushort* calog= canon + coff[8];
    const ushort* cdssm= canon + coff[9];
    const ushort* copw = canon + coff[10];
    const ushort* copb = canon + coff[11];
    const ushort* cln1g= canon + coff[12];
    const ushort* cln1b= canon + coff[13];
    const ushort* cf1w = canon + coff[14];
    const ushort* cf1b = canon + coff[15];
    const ushort* cf2w = canon + coff[16];
    const ushort* cf2b = canon + coff[17];
    const ushort* cln2g= canon + coff[18];
    const ushort* cln2b= canon + coff[19];

    // pipeline buffers
    ushort* xz   = (ushort*)(ws + 8388608);     // [8192,1024] bf16
    ushort* xc   = (ushort*)(ws + 25165824);    // [8192,512]  bf16
    float*  dt   = (float*)(ws + 33554432);     // [8192,512]  f32
    float*  Bsb  = (float*)(ws + 50331648);     // [8192,16]
    float*  Csb  = (float*)(ws + 50855936);     // [8192,16]
    float*  summ = (float*)(ws + 51380224);     // [4,32,32,512]
    float*  hin  = (float*)(ws + 59768832);     // [4,32,16,512]
    ushort* yb   = (ushort*)(ws + 63963136);    // [8192,512]  bf16
    // phase-2 aliases (phase-1 buffers dead)
    float*  sout = (float*)(ws + 8388608);      // [8192,256] f32
    float*  y1f  = (float*)(ws + 16777216);     // [8192,256] f32
    ushort* y1b  = (ushort*)(ws + 25165824);    // [8192,256] bf16
    ushort* f1   = (ushort*)(ws + 29360128);    // [8192,1024] bf16
    float*  ffn  = (float*)(ws + 46137344);     // [8192,256] f32

    sniff_k<<<1, 64, 0, stream>>>((const ushort*)d_in[0], flag);
    canon_k<<<(ctot + 255) / 256, 256, 0, stream>>>(ca, canon, flag);

    // 1. in_proj
    gemm_bt<128, 128, 0, false, true><<<dim3(64, 8), 256, 0, stream>>>(
        cx, cipw, cipb, nullptr, xz, 8192, 1024, 256);
    // 2. conv + silu
    conv_silu_k<<<16384, 256, 0, stream>>>(xz, ccw, ccb, xc);
    // 3. x_proj + dt_proj
    xproj_dt_k<<<8192, 256, 0, stream>>>(xc, cxpw, cdtw, cdtb, dt, Bsb, Csb);
    // 4-6. chunked scan
    scan1_k<<<dim3(2, 32, 4), 256, 0, stream>>>(dt, xc, Bsb, calog, summ);
    combine_k<<<64, 512, 0, stream>>>(summ, hin);
    scan2_k<<<dim3(2, 32, 4), 256, 0, stream>>>(dt, xc, Bsb, Csb, calog, hin, xz, cdssm, yb);
    // 7. out_proj
    gemm_bt<128, 64, 0, true, false><<<dim3(64, 4), 256, 0, stream>>>(
        yb, copw, copb, sout, nullptr, 8192, 256, 512);
    // 8. y1 = LN(x + sout)
    ln1_k<<<8192, 256, 0, stream>>>(d_in[0], sout, cln1g, cln1b, y1f, y1b, flag);
    // 9. f1 = gelu(y1 @ f1w^T)
    gemm_bt<128, 128, 1, false, true><<<dim3(64, 8), 256, 0, stream>>>(
        y1b, cf1w, cf1b, nullptr, f1, 8192, 1024, 256);
    // 10. ffn = gelu(f1 @ f2w^T)
    gemm_bt<128, 64, 1, true, false><<<dim3(64, 4), 256, 0, stream>>>(
        f1, cf2w, cf2b, ffn, nullptr, 8192, 256, 1024);
    // 11. out = LN(y1 + ffn)
    ln2_k<<<8192, 256, 0, stream>>>(y1f, ffn, cln2g, cln2b, d_out, flag);
}

// Round 3
// 268.343 us; speedup vs baseline: 1.2539x; 1.2539x over previous
//
#include <hip/hip_runtime.h>

typedef __bf16 bf16x8 __attribute__((ext_vector_type(8)));
typedef float  f32x4  __attribute__((ext_vector_type(4)));

#define AS1 __attribute__((address_space(1)))
#define AS3 __attribute__((address_space(3)))

__device__ __forceinline__ float bf2f(ushort u) {
    union { unsigned int i; float f; } v; v.i = ((unsigned int)u) << 16; return v.f;
}
__device__ __forceinline__ ushort f2bf(float f) {
    union { float f; unsigned int i; } v; v.f = f;
    unsigned int i = v.i;
    unsigned int r = i + 0x7FFFu + ((i >> 16) & 1u);   // RNE
    return (ushort)(r >> 16);
}
__device__ __forceinline__ float bflo(unsigned int u) { return bf2f((ushort)(u & 0xFFFFu)); }
__device__ __forceinline__ float bfhi(unsigned int u) { return bf2f((ushort)(u >> 16)); }

// ---------------------------------------------------------------------------
// dtype sniff: bf16 N(0,1) data -> ~256/256 sane u16s; f32 data -> ~140/256
// ---------------------------------------------------------------------------
__global__ void sniff_k(const ushort* __restrict__ x, int* __restrict__ flag)
{
    const int lane = threadIdx.x;
    int cnt = 0;
    #pragma unroll
    for (int r = 0; r < 4; r++) {
        const ushort u = x[lane + r * 64];
        const int e = (u >> 7) & 0xFF;
        if ((u & 0x7FFF) == 0 || (e >= 112 && e <= 141)) cnt++;
    }
    #pragma unroll
    for (int o = 32; o > 0; o >>= 1) cnt += __shfl_down(cnt, o);
    if (lane == 0) flag[0] = (cnt >= 224) ? 1 : 0;
}

// ---------------------------------------------------------------------------
// canonicalize all inputs into packed bf16 region
// ---------------------------------------------------------------------------
struct CanonArgs {
    const void* src[20];
    int off[20];
    int total;
};

__launch_bounds__(256)
__global__ void canon_k(CanonArgs a, ushort* __restrict__ dst, const int* __restrict__ flag)
{
    const int i = blockIdx.x * 256 + threadIdx.x;
    if (i >= a.total) return;
    const int fl = flag[0];
    int s = 0;
    #pragma unroll
    for (int t = 1; t < 20; t++) if (i >= a.off[t]) s = t;
    const int li = i - a.off[s];
    ushort v;
    if (fl) v = ((const ushort*)a.src[s])[li];
    else    v = f2bf(((const float*)a.src[s])[li]);
    dst[i] = v;
}

// zero-padded weights: dtw [512,16]->[512,32], xpw [48,512]->[64,512]
__launch_bounds__(256)
__global__ void prep_k(const ushort* __restrict__ dtw, const ushort* __restrict__ xpw,
                       ushort* __restrict__ dtw_pad, ushort* __restrict__ xpw_pad)
{
    const int i = blockIdx.x * 256 + threadIdx.x;   // 49152
    if (i < 16384) {
        const int dd = i >> 5, r = i & 31;
        dtw_pad[i] = (r < 16) ? dtw[dd * 16 + r] : (ushort)0;
    } else {
        const int j = i - 16384;
        const int r = j >> 9;
        xpw_pad[j] = (r < 48) ? xpw[j] : (ushort)0;
    }
}

// ---------------------------------------------------------------------------
// GEMM: C[M,N] = act(A[M,K](bf16,lda) @ W[N,K]^T(bf16) + bias[N])
// ACT: 0 none, 1 gelu, 2 softplus
// ---------------------------------------------------------------------------
template<int BM, int BN, int ACT, bool HASB, bool WF32, bool WBF16>
__launch_bounds__(256, 2)
__global__ void gemm_bt(const ushort* __restrict__ A, const ushort* __restrict__ W,
                        const ushort* __restrict__ bias,
                        float* __restrict__ Cf, ushort* __restrict__ Cb,
                        int M, int N, int K, int lda)
{
    constexpr int WMT = BM / 32;
    constexpr int WNT = BN / 32;
    __shared__ __align__(16) ushort As[BM * 32];
    __shared__ __align__(16) ushort Bs[BN * 32];
    const int tid  = threadIdx.x;
    const int wave = tid >> 6;
    const int lane = tid & 63;
    const int m0 = blockIdx.x * BM;
    const int n0 = blockIdx.y * BN;
    const int wm = (wave >> 1) * (BM / 2);
    const int wn = (wave & 1) * (BN / 2);
    const int lrow = lane & 15;
    const int quad = lane >> 4;

    f32x4 acc[WMT][WNT];
    #pragma unroll
    for (int i = 0; i < WMT; i++)
        #pragma unroll
        for (int j = 0; j < WNT; j++)
            #pragma unroll
            for (int r = 0; r < 4; r++) acc[i][j][r] = 0.f;

    for (int k0 = 0; k0 < K; k0 += 32) {
        #pragma unroll
        for (int t = 0; t < BM / 64; t++) {
            const int inst = t * 4 + wave;
            const int row  = inst * 16 + (lane >> 2);
            const int sub  = lane & 3;
            const ushort* gp = A + (size_t)(m0 + row) * lda + (k0 + sub * 8);
            __builtin_amdgcn_global_load_lds((AS1 void*)(void*)gp,
                                             (AS3 void*)(As + inst * 512), 16, 0, 0);
        }
        #pragma unroll
        for (int t = 0; t < BN / 64; t++) {
            const int inst = t * 4 + wave;
            const int row  = inst * 16 + (lane >> 2);
            const int sub  = lane & 3;
            const ushort* gp = W + (size_t)(n0 + row) * K + (k0 + sub * 8);
            __builtin_amdgcn_global_load_lds((AS1 void*)(void*)gp,
                                             (AS3 void*)(Bs + inst * 512), 16, 0, 0);
        }
        __syncthreads();

        bf16x8 afr[WMT], bfr[WNT];
        #pragma unroll
        for (int i = 0; i < WMT; i++)
            afr[i] = *(const bf16x8*)&As[(wm + i * 16 + lrow) * 32 + quad * 8];
        #pragma unroll
        for (int j = 0; j < WNT; j++)
            bfr[j] = *(const bf16x8*)&Bs[(wn + j * 16 + lrow) * 32 + quad * 8];
        #pragma unroll
        for (int i = 0; i < WMT; i++)
            #pragma unroll
            for (int j = 0; j < WNT; j++)
                acc[i][j] = __builtin_amdgcn_mfma_f32_16x16x32_bf16(afr[i], bfr[j], acc[i][j], 0, 0, 0);
        __syncthreads();
    }

    // epilogue: C/D layout col(n)=lane&15, row(m)=quad*4+reg  [m89/m91]
    #pragma unroll
    for (int i = 0; i < WMT; i++) {
        const int gm = m0 + wm + i * 16 + quad * 4;
        #pragma unroll
        for (int j = 0; j < WNT; j++) {
            const int gn = n0 + wn + j * 16 + lrow;
            const float bv = HASB ? bf2f(bias[gn]) : 0.f;
            #pragma unroll
            for (int r = 0; r < 4; r++) {
                float v = acc[i][j][r] + bv;
                if (ACT == 1) v = 0.5f * v * (1.f + erff(v * 0.70710678118654752f));
                if (ACT == 2) v = (v > 15.f) ? v : __logf(1.f + __expf(v));
                const size_t off = (size_t)(gm + r) * N + gn;
                if (WF32)  Cf[off] = v;
                if (WBF16) Cb[off] = f2bf(v);
            }
        }
    }
}

// ---------------------------------------------------------------------------
// depthwise causal conv (DC=4) + SiLU, 8 d's per thread, uint4 loads
// ---------------------------------------------------------------------------
__launch_bounds__(256)
__global__ void conv_silu_k(const ushort* __restrict__ xz, const ushort* __restrict__ cw,
                            const ushort* __restrict__ cb, ushort* __restrict__ xc)
{
    const int idx = blockIdx.x * 256 + threadIdx.x;   // [0, 8192*64)
    const int t  = idx >> 6;
    const int d8 = (idx & 63) * 8;
    const int l  = t & 2047;

    ushort wl[32];
    *(uint4*)&wl[0]  = *(const uint4*)&cw[d8 * 4];
    *(uint4*)&wl[8]  = *(const uint4*)&cw[d8 * 4 + 8];
    *(uint4*)&wl[16] = *(const uint4*)&cw[d8 * 4 + 16];
    *(uint4*)&wl[24] = *(const uint4*)&cw[d8 * 4 + 24];

    ushort bl[8];
    *(uint4*)&bl[0] = *(const uint4*)&cb[d8];

    float acc[8];
    #pragma unroll
    for (int j = 0; j < 8; j++) acc[j] = bf2f(bl[j]);

    #pragma unroll
    for (int k = 0; k < 4; k++) {
        const int ls = l - 3 + k;
        if (ls >= 0) {
            ushort xl[8];
            *(uint4*)&xl[0] = *(const uint4*)&xz[(size_t)(t - 3 + k) * 1024 + d8];
            #pragma unroll
            for (int j = 0; j < 8; j++) acc[j] += bf2f(xl[j]) * bf2f(wl[j * 4 + k]);
        }
    }
    ushort ol[8];
    #pragma unroll
    for (int j = 0; j < 8; j++) {
        const float s = acc[j] / (1.f + __expf(-acc[j]));
        ol[j] = f2bf(s);
    }
    *(uint4*)&xc[(size_t)idx * 8] = *(uint4*)&ol[0];
}

// ---------------------------------------------------------------------------
// chunked scan: 64 chunks x 32 steps.  grid (2, 64, 4), 256 thr
// B/C live in xdbl_f[8192,64] cols 16..31 / 32..47
// ---------------------------------------------------------------------------
__launch_bounds__(256)
__global__ void scan1_k(const float* __restrict__ dt, const ushort* __restrict__ xc,
                        const float* __restrict__ xdbl, const ushort* __restrict__ Alog,
                        float* __restrict__ summ)
{
    __shared__ float Bsh[32 * 16];
    const int tid = threadIdx.x;
    const int c = blockIdx.y, b = blockIdx.z;
    const int t0 = b * 2048 + c * 32;
    for (int e = tid; e < 512; e += 256)
        Bsh[e] = xdbl[(size_t)(t0 + (e >> 4)) * 64 + 16 + (e & 15)];
    __syncthreads();
    const int d = blockIdx.x * 256 + tid;
    float A[16], h[16];
    #pragma unroll
    for (int n = 0; n < 16; n++) {
        A[n] = -__expf(bf2f(Alog[d * 16 + n]));
        h[n] = 0.f;
    }
    float sdt = 0.f;
    for (int i = 0; i < 32; i++) {
        const int t = t0 + i;
        const float dtv = dt[(size_t)t * 512 + d];
        const float xiv = bf2f(xc[(size_t)t * 512 + d]);
        const float dx = dtv * xiv;
        sdt += dtv;
        const float* Br = &Bsh[i * 16];
        #pragma unroll
        for (int n = 0; n < 16; n++) {
            const float da = __expf(dtv * A[n]);
            h[n] = da * h[n] + dx * Br[n];
        }
    }
    const size_t base = ((size_t)(b * 64 + c) * 32) * 512 + d;
    #pragma unroll
    for (int n = 0; n < 16; n++) summ[base + (size_t)n * 512] = __expf(A[n] * sdt);
    #pragma unroll
    for (int n = 0; n < 16; n++) summ[base + (size_t)(16 + n) * 512] = h[n];
}

// sequential combine over 64 chunks; overwrites p-slot with h_in (in-place)
__launch_bounds__(512)
__global__ void combine_k(float* __restrict__ summ)
{
    const int b = blockIdx.x >> 4, n = blockIdx.x & 15;
    const int d = threadIdx.x;
    float h = 0.f;
    for (int c = 0; c < 64; c++) {
        const size_t sb = ((size_t)((b * 64 + c) * 32 + n)) * 512 + d;
        const float p  = summ[sb];
        const float hl = summ[sb + 8192];
        summ[sb] = h;
        h = p * h + hl;
    }
}

// pass2: replay chunk from h_in; writes y in-place over xc (same thread+addr)
__launch_bounds__(256)
__global__ void scan2_k(const float* __restrict__ dt, ushort* xc,
                        const float* __restrict__ xdbl, const ushort* __restrict__ Alog,
                        const float* __restrict__ summ, const ushort* __restrict__ xz,
                        const ushort* __restrict__ Dssm)
{
    __shared__ float Bsh[32 * 16];
    __shared__ float Csh[32 * 16];
    const int tid = threadIdx.x;
    const int c = blockIdx.y, b = blockIdx.z;
    const int t0 = b * 2048 + c * 32;
    for (int e = tid; e < 512; e += 256) {
        const size_t rb = (size_t)(t0 + (e >> 4)) * 64 + (e & 15);
        Bsh[e] = xdbl[rb + 16];
        Csh[e] = xdbl[rb + 32];
    }
    __syncthreads();
    const int d = blockIdx.x * 256 + tid;
    float A[16], h[16];
    #pragma unroll
    for (int n = 0; n < 16; n++) A[n] = -__expf(bf2f(Alog[d * 16 + n]));
    const size_t base = ((size_t)(b * 64 + c) * 32) * 512 + d;
    #pragma unroll
    for (int n = 0; n < 16; n++) h[n] = summ[base + (size_t)n * 512];
    const float Dv = bf2f(Dssm[d]);
    for (int i = 0; i < 32; i++) {
        const int t = t0 + i;
        const float dtv = dt[(size_t)t * 512 + d];
        const float xiv = bf2f(xc[(size_t)t * 512 + d]);
        const float dx = dtv * xiv;
        const float* Br = &Bsh[i * 16];
        const float* Cr = &Csh[i * 16];
        float yv = 0.f;
        #pragma unroll
        for (int n = 0; n < 16; n++) {
            const float da = __expf(dtv * A[n]);
            h[n] = da * h[n] + dx * Br[n];
            yv += h[n] * Cr[n];
        }
        yv += xiv * Dv;
        const float zv = bf2f(xz[(size_t)t * 1024 + 512 + d]);
        yv *= zv / (1.f + __expf(-zv));
        xc[(size_t)t * 512 + d] = f2bf(yv);   // yb in-place
    }
}

// ---------------------------------------------------------------------------
// LayerNorms: one wave per token (4 tokens/block), 4 elems/lane, butterfly
// ---------------------------------------------------------------------------
__launch_bounds__(256)
__global__ void ln1_k(const void* __restrict__ xin, const float* __restrict__ sout,
                      const ushort* __restrict__ g, const ushort* __restrict__ bb,
                      float* __restrict__ y1f, ushort* __restrict__ y1b,
                      const int* __restrict__ flag)
{
    const int w = threadIdx.x >> 6, l = threadIdx.x & 63;
    const int t = blockIdx.x * 4 + w;
    const size_t base = (size_t)t * 256 + l * 4;
    const int fl = flag[0];
    float v[4];
    if (fl) {
        const uint2 xr = *(const uint2*)((const ushort*)xin + base);
        v[0] = bflo(xr.x); v[1] = bfhi(xr.x); v[2] = bflo(xr.y); v[3] = bfhi(xr.y);
    } else {
        const float4 xr = *(const float4*)((const float*)xin + base);
        v[0] = xr.x; v[1] = xr.y; v[2] = xr.z; v[3] = xr.w;
    }
    const float4 sv = *(const float4*)&sout[base];
    v[0] += sv.x; v[1] += sv.y; v[2] += sv.z; v[3] += sv.w;
    float s = v[0] + v[1] + v[2] + v[3];
    #pragma unroll
    for (int o = 32; o > 0; o >>= 1) s += __shfl_xor(s, o);
    const float mean = s * (1.f / 256.f);
    float q = 0.f;
    #pragma unroll
    for (int j = 0; j < 4; j++) { const float dv = v[j] - mean; q += dv * dv; }
    #pragma unroll
    for (int o = 32; o > 0; o >>= 1) q += __shfl_xor(q, o);
    const float r = rsqrtf(q * (1.f / 256.f) + 1e-5f);
    const uint2 gv = *(const uint2*)&g[l * 4];
    const uint2 bv = *(const uint2*)&bb[l * 4];
    const float gf[4] = { bflo(gv.x), bfhi(gv.x), bflo(gv.y), bfhi(gv.y) };
    const float bf[4] = { bflo(bv.x), bfhi(bv.x), bflo(bv.y), bfhi(bv.y) };
    float4 of;
    float* op = (float*)&of;
    ushort ob[4];
    #pragma unroll
    for (int j = 0; j < 4; j++) {
        const float o2 = (v[j] - mean) * r * gf[j] + bf[j];
        op[j] = o2; ob[j] = f2bf(o2);
    }
    *(float4*)&y1f[base] = of;
    *(uint2*)&y1b[base] = *(uint2*)&ob[0];
}

__launch_bounds__(256)
__global__ void ln2_k(const float* __restrict__ y1f, const float* __restrict__ ffn,
                      const ushort* __restrict__ g, const ushort* __restrict__ bb,
                      void* __restrict__ out, const int* __restrict__ flag)
{
    const int w = threadIdx.x >> 6, l = threadIdx.x & 63;
    const int t = blockIdx.x * 4 + w;
    const size_t base = (size_t)t * 256 + l * 4;
    const int fl = flag[0];
    const float4 av = *(const float4*)&y1f[base];
    const float4 fv = *(const float4*)&ffn[base];
    float v[4] = { av.x + fv.x, av.y + fv.y, av.z + fv.z, av.w + fv.w };
    float s = v[0] + v[1] + v[2] + v[3];
    #pragma unroll
    for (int o = 32; o > 0; o >>= 1) s += __shfl_xor(s, o);
    const float mean = s * (1.f / 256.f);
    float q = 0.f;
    #pragma unroll
    for (int j = 0; j < 4; j++) { const float dv = v[j] - mean; q += dv * dv; }
    #pragma unroll
    for (int o = 32; o > 0; o >>= 1) q += __shfl_xor(q, o);
    const float r = rsqrtf(q * (1.f / 256.f) + 1e-5f);
    const uint2 gv = *(const uint2*)&g[l * 4];
    const uint2 bv = *(const uint2*)&bb[l * 4];
    const float gf[4] = { bflo(gv.x), bfhi(gv.x), bflo(gv.y), bfhi(gv.y) };
    const float bf[4] = { bflo(bv.x), bfhi(bv.x), bflo(bv.y), bfhi(bv.y) };
    if (fl) {
        ushort ob[4];
        #pragma unroll
        for (int j = 0; j < 4; j++) ob[j] = f2bf((v[j] - mean) * r * gf[j] + bf[j]);
        *(uint2*)((ushort*)out + base) = *(uint2*)&ob[0];
    } else {
        float4 of;
        float* op = (float*)&of;
        #pragma unroll
        for (int j = 0; j < 4; j++) op[j] = (v[j] - mean) * r * gf[j] + bf[j];
        *(float4*)((float*)out + base) = of;
    }
}

// ---------------------------------------------------------------------------
extern "C" void kernel_launch(void* const* d_in, const int* in_sizes, int n_in,
                              void* d_out, int out_size, void* d_ws, size_t ws_size,
                              hipStream_t stream)
{
    char* ws = (char*)d_ws;
    int*    flag  = (int*)(ws + 0);
    ushort* canon = (ushort*)(ws + 256);

    static const int coff[20] = {
        0,        2097152,  2359296,  2360320,  2362368,
        2362880,  2387456,  2395648,  2396160,  2404352,
        2404864,  2535936,  2536192,  2536448,  2536704,
        2798848,  2799872,  3062016,  3062272,  3062528 };
    static const int ctot = 3062784;

    CanonArgs ca;
    for (int i = 0; i < 20; i++) { ca.src[i] = d_in[i]; ca.off[i] = coff[i]; }
    ca.total = ctot;

    const ushort* cx   = canon + coff[0];
    const ushort* cipw = canon + coff[1];
    const ushort* cipb = canon + coff[2];
    const ushort* ccw  = canon + coff[3];
    const ushort* ccb  = canon + coff[4];
    const ushort* cxpw = canon + coff[5];
    const ushort* cdtw = canon + coff[6];
    const ushort* cdtb = canon + coff[7];
    const ushort* calog= canon + coff[8];
    const ushort* cdssm= canon + coff[9];
    const ushort* copw = canon + coff[10];
    const ushort* copb = canon + coff[11];
    const ushort* cln1g= canon + coff[12];
    const ushort* cln1b= canon + coff[13];
    const ushort* cf1w = canon + coff[14];
    const ushort* cf1b = canon + coff[15];
    const ushort* cf2w = canon + coff[16];
    const ushort* cf2b = canon + coff[17];
    const ushort* cln2g= canon + coff[18];
    const ushort* cln2b= canon + coff[19];

    // phase-1 buffers
    ushort* xpw_pad = (ushort*)(ws + 6291456);  // [64,512] bf16
    ushort* dtw_pad = (ushort*)(ws + 6356992);  // [512,32] bf16
    ushort* xz      = (ushort*)(ws + 8388608);  // [8192,1024] bf16, 16 MB
    ushort* xc      = (ushort*)(ws + 25165824); // [8192,512] bf16, 8 MB (yb in-place later)
    float*  xdbl_f  = (float*)(ws + 33554432);  // [8192,64] f32, 2 MB
    ushort* xdbl_b  = (ushort*)(ws + 35651584); // [8192,64] bf16, 1 MB
    float*  dt      = (float*)(ws + 36700160);  // [8192,512] f32, 16 MB
    float*  summ    = (float*)(ws + 53477376);  // [4,64,32,512] f32, 16 MB
    // phase-2 aliases
    float*  sout = (float*)(ws + 8388608);      // [8192,256] f32 (over xz lo)
    float*  y1f  = (float*)(ws + 16777216);     // [8192,256] f32 (over xz hi)
    ushort* y1b  = (ushort*)(ws + 33554432);    // [8192,256] bf16 (over xdbl)
    ushort* f1   = (ushort*)(ws + 37748736);    // [8192,1024] bf16 (over dt/summ lo)
    float*  ffn  = (float*)(ws + 54525952);     // [8192,256] f32 (over summ)
    ushort* yb   = xc;

    sniff_k<<<1, 64, 0, stream>>>((const ushort*)d_in[0], flag);
    canon_k<<<(ctot + 255) / 256, 256, 0, stream>>>(ca, canon, flag);
    prep_k<<<192, 256, 0, stream>>>(cdtw, cxpw, dtw_pad, xpw_pad);

    // 1. in_proj: xz = x @ ipw^T + ipb
    gemm_bt<128, 128, 0, true, false, true><<<dim3(64, 8), 256, 0, stream>>>(
        cx, cipw, cipb, nullptr, xz, 8192, 1024, 256, 256);
    // 2. conv + silu -> xc
    conv_silu_k<<<2048, 256, 0, stream>>>(xz, ccw, ccb, xc);
    // 3a. xdbl = xc @ xpw_pad^T   [8192,64] (f32 + bf16)
    gemm_bt<64, 64, 0, false, true, true><<<dim3(128, 1), 256, 0, stream>>>(
        xc, xpw_pad, nullptr, xdbl_f, xdbl_b, 8192, 64, 512, 512);
    // 3b. dt = softplus(xdbl[:, :32] @ dtw_pad^T + dtb)  [8192,512]
    gemm_bt<128, 64, 2, true, true, false><<<dim3(64, 8), 256, 0, stream>>>(
        xdbl_b, dtw_pad, cdtb, dt, nullptr, 8192, 512, 32, 64);
    // 4-6. chunked scan (64 chunks x 32 steps)
    scan1_k<<<dim3(2, 64, 4), 256, 0, stream>>>(dt, xc, xdbl_f, calog, summ);
    combine_k<<<64, 512, 0, stream>>>(summ);
    scan2_k<<<dim3(2, 64, 4), 256, 0, stream>>>(dt, xc, xdbl_f, calog, summ, xz, cdssm);
    // 7. out_proj: sout = yb @ opw^T + opb
    gemm_bt<128, 64, 0, true, true, false><<<dim3(64, 4), 256, 0, stream>>>(
        yb, copw, copb, sout, nullptr, 8192, 256, 512, 512);
    // 8. y1 = LN(x + sout)
    ln1_k<<<2048, 256, 0, stream>>>(d_in[0], sout, cln1g, cln1b, y1f, y1b, flag);
    // 9. f1 = gelu(y1 @ f1w^T + f1b)
    gemm_bt<128, 128, 1, true, false, true><<<dim3(64, 8), 256, 0, stream>>>(
        y1b, cf1w, cf1b, nullptr, f1, 8192, 1024, 256, 256);
    // 10. ffn = gelu(f1 @ f2w^T + f2b)
    gemm_bt<128, 64, 1, true, true, false><<<dim3(64, 4), 256, 0, stream>>>(
        f1, cf2w, cf2b, ffn, nullptr, 8192, 256, 1024, 1024);
    // 11. out = LN(y1 + ffn)
    ln2_k<<<2048, 256, 0, stream>>>(y1f, ffn, cln2g, cln2b, d_out, flag);
}